// Round 1
// baseline (529.726 us; speedup 1.0000x reference)
//
#include <hip/hip_runtime.h>
#include <hip/hip_bf16.h>
#include <stdint.h>

#define EPSF 1e-5f

typedef __attribute__((ext_vector_type(8))) short short8;
typedef __attribute__((ext_vector_type(4))) float f32x4;

__device__ inline short f2bf(float f) {
    union { float f; unsigned u; } x; x.f = f;
    unsigned u = x.u;
    unsigned r = (u + 0x7FFFu + ((u >> 16) & 1u)) >> 16;  // round-to-nearest-even
    return (short)r;
}

__device__ inline f32x4 mfma16x16x32(short8 a, short8 b, f32x4 c) {
    return __builtin_amdgcn_mfma_f32_16x16x32_bf16(a, b, c, 0, 0, 0);
}

// ---------------------------------------------------------------------------
// BT-GEMM: C[M,N] = A[M,KP] * B[N,KP]^T   (A,B bf16-as-short, KP % 32 == 0)
// MODE 0: full-K, C = f32, += bias[col] if bias != nullptr
// MODE 1: split-K over blockIdx.z, partials to C + z*M*ldc, no bias
// Tile: 128x128, BK=32, 4 waves (2x2), each wave 64x64 via 4x4 MFMA frags.
// ---------------------------------------------------------------------------
template <int MODE>
__global__ __launch_bounds__(256) void gemm_bt(
    const short* __restrict__ A, const short* __restrict__ B,
    float* __restrict__ C, int M, int N, int KP, int ldc,
    const float* __restrict__ bias, int klen)
{
    __shared__ alignas(16) short As[128 * 32];
    __shared__ alignas(16) short Bs[128 * 32];

    const int tid = threadIdx.x;
    const int l   = tid & 63;
    const int w   = tid >> 6;
    const int wr  = w >> 1, wc = w & 1;
    const int m0  = blockIdx.x * 128;
    const int n0  = blockIdx.y * 128;

    int k_beg = 0, k_end = KP;
    if (MODE == 1) { k_beg = blockIdx.z * klen; k_end = k_beg + klen; }

    const int sr = l >> 2;        // staging row within 16-row group
    const int sc = (l & 3) * 8;   // staging bf16-col offset
    const int lr = l & 15;        // MFMA row/col lane index
    const int kg = l >> 4;        // MFMA k-group

    f32x4 acc[4][4] = {};

    for (int k0 = k_beg; k0 < k_end; k0 += 32) {
#pragma unroll
        for (int i = 0; i < 2; ++i) {
            const int g  = w * 2 + i;                 // 16-row group 0..7
            const int rA = m0 + g * 16 + sr;
            const short* ga = A + (size_t)rA * KP + k0 + sc;
            __builtin_amdgcn_global_load_lds(
                (const __attribute__((address_space(1))) void*)ga,
                (__attribute__((address_space(3))) void*)(&As[g * 512]), 16, 0, 0);
            int rB = n0 + g * 16 + sr;
            if (rB > N - 1) rB = N - 1;               // clamp: keep reads in-bounds
            const short* gb = B + (size_t)rB * KP + k0 + sc;
            __builtin_amdgcn_global_load_lds(
                (const __attribute__((address_space(1))) void*)gb,
                (__attribute__((address_space(3))) void*)(&Bs[g * 512]), 16, 0, 0);
        }
        __syncthreads();   // compiler drains vmcnt before s_barrier

        short8 af[4], bfr[4];
#pragma unroll
        for (int mi = 0; mi < 4; ++mi)
            af[mi] = *(const short8*)&As[(wr * 64 + mi * 16 + lr) * 32 + kg * 8];
#pragma unroll
        for (int ni = 0; ni < 4; ++ni)
            bfr[ni] = *(const short8*)&Bs[(wc * 64 + ni * 16 + lr) * 32 + kg * 8];
#pragma unroll
        for (int mi = 0; mi < 4; ++mi)
#pragma unroll
            for (int ni = 0; ni < 4; ++ni)
                acc[mi][ni] = mfma16x16x32(af[mi], bfr[ni], acc[mi][ni]);
        __syncthreads();
    }

    float* Cb = C;
    if (MODE == 1) Cb = C + (size_t)blockIdx.z * M * ldc;

#pragma unroll
    for (int ni = 0; ni < 4; ++ni) {
        int col = n0 + wc * 64 + ni * 16 + lr;
        if (col >= N) continue;
        float bv = (MODE == 0 && bias) ? bias[col] : 0.0f;
#pragma unroll
        for (int mi = 0; mi < 4; ++mi) {
            int row0 = m0 + wr * 64 + mi * 16 + kg * 4;
#pragma unroll
            for (int r = 0; r < 4; ++r)
                Cb[(size_t)(row0 + r) * ldc + col] = acc[mi][ni][r] + bv;
        }
    }
}

// ---------------------------------------------------------------------------
// gather entity row + BN0 (scalar channel) -> f32 x[2048,400]
// ---------------------------------------------------------------------------
__global__ void gather_bn0(const float* __restrict__ E, const int* __restrict__ idx,
                           const float* g, const float* bb, const float* m,
                           const float* v, float* __restrict__ xout)
{
    int b = blockIdx.x;
    int e = idx[b];
    float s = g[0] * rsqrtf(v[0] + EPSF);
    float t = bb[0] - m[0] * s;
    const float4* src = (const float4*)(E + (size_t)e * 400);
    float4* dst = (float4*)(xout + (size_t)b * 400);
    for (int i = threadIdx.x; i < 100; i += blockDim.x) {
        float4 u = src[i];
        dst[i] = make_float4(u.x * s + t, u.y * s + t, u.z * s + t, u.w * s + t);
    }
}

// gather relation row -> bf16, padded to 416 cols with zeros
__global__ void gather_r_pad(const float* __restrict__ R, const int* __restrict__ idx,
                             short* __restrict__ rout)
{
    int b = blockIdx.x;
    int r = idx[b];
    const float* src = R + (size_t)r * 400;
    short* dst = rout + (size_t)b * 416;
    for (int i = threadIdx.x; i < 416; i += blockDim.x)
        dst[i] = (i < 400) ? f2bf(src[i]) : (short)0;
}

// fc_w (400 x 37632) f32 -> bf16, same layout
__global__ void cvt_fcw(const float* __restrict__ in, short* __restrict__ out, int n4)
{
    int i = blockIdx.x * blockDim.x + threadIdx.x;
    int stride = gridDim.x * blockDim.x;
    const float4* in4 = (const float4*)in;
    short4* out4 = (short4*)out;
    for (; i < n4; i += stride) {
        float4 v = in4[i];
        out4[i] = make_short4(f2bf(v.x), f2bf(v.y), f2bf(v.z), f2bf(v.w));
    }
}

// fc1_w (864 x 400) f32 -> bf16 padded to ld 416
__global__ void cvt_fc1w_pad(const float* __restrict__ in, short* __restrict__ out)
{
    int i = blockIdx.x * blockDim.x + threadIdx.x;
    if (i >= 864 * 416) return;
    int row = i / 416, col = i - row * 416;
    out[i] = (col < 400) ? f2bf(in[row * 400 + col]) : (short)0;
}

// ---------------------------------------------------------------------------
// per-sample conv (96 out-ch, 9 taps, valid) + BN1 -> bf16 flat[b, o*392+l]
// one block per sample; x row + filter row staged in LDS
// ---------------------------------------------------------------------------
__global__ __launch_bounds__(256) void conv_bn1(
    const float* __restrict__ xall, const float* __restrict__ kfall,
    const float* __restrict__ g1, const float* __restrict__ b1,
    const float* __restrict__ m1, const float* __restrict__ v1,
    short* __restrict__ flat, int b_base)
{
    __shared__ float xs[400];
    __shared__ float ks[864];
    __shared__ float s1s[96], t1s[96];
    const int b = b_base + blockIdx.x;
    const int tid = threadIdx.x;
    const float* xr = xall + (size_t)b * 400;
    const float* kr = kfall + (size_t)b * 864;
    for (int i = tid; i < 400; i += 256) xs[i] = xr[i];
    for (int i = tid; i < 864; i += 256) ks[i] = kr[i];
    if (tid < 96) {
        float s = g1[tid] * rsqrtf(v1[tid] + EPSF);
        s1s[tid] = s;
        t1s[tid] = b1[tid] - m1[tid] * s;
    }
    __syncthreads();
    short* fr = flat + (size_t)blockIdx.x * 37632;
    for (int idx = tid; idx < 37632; idx += 256) {
        int o  = idx / 392;
        int ll = idx - o * 392;
        float a = 0.f;
#pragma unroll
        for (int f = 0; f < 9; ++f) a += xs[ll + f] * ks[o * 9 + f];
        fr[idx] = f2bf(a * s1s[o] + t1s[o]);
    }
}

// sum 8 split-K partials + fc_b + BN2 + ReLU -> bf16 x_out rows, ld 416 (pad=0)
__global__ void reduce_bn2(const float* __restrict__ hp, int C,
                           const float* __restrict__ fcb,
                           const float* __restrict__ g2, const float* __restrict__ b2,
                           const float* __restrict__ m2, const float* __restrict__ v2,
                           short* __restrict__ xout, int cb)
{
    int i = blockIdx.x * blockDim.x + threadIdx.x;
    int total = C * 416;
    if (i >= total) return;
    int row = i / 416, col = i - row * 416;
    short val = 0;
    if (col < 400) {
        float s = 0.f;
        size_t stride = (size_t)C * 400;
        size_t basei = (size_t)row * 400 + col;
#pragma unroll
        for (int k = 0; k < 8; ++k) s += hp[k * stride + basei];
        float sc = g2[col] * rsqrtf(v2[col] + EPSF);
        float hv = (s + fcb[col] - m2[col]) * sc + b2[col];
        val = f2bf(fmaxf(hv, 0.f));
    }
    xout[(size_t)(cb + row) * 416 + col] = val;
}

extern "C" void kernel_launch(void* const* d_in, const int* in_sizes, int n_in,
                              void* d_out, int out_size, void* d_ws, size_t ws_size,
                              hipStream_t stream)
{
    (void)in_sizes; (void)n_in; (void)out_size;
    const int*   e1    = (const int*)d_in[0];
    const int*   r1i   = (const int*)d_in[1];
    const int*   r2i   = (const int*)d_in[2];
    const int*   e2    = (const int*)d_in[3];
    const float* E_w   = (const float*)d_in[4];
    const float* R_w   = (const float*)d_in[5];
    const float* fc1_w = (const float*)d_in[6];
    const float* fc1_b = (const float*)d_in[7];
    const float* fc_w  = (const float*)d_in[8];
    const float* fc_b  = (const float*)d_in[9];
    const float* bn0_g = (const float*)d_in[10];
    const float* bn0_b = (const float*)d_in[11];
    const float* bn0_m = (const float*)d_in[12];
    const float* bn0_v = (const float*)d_in[13];
    const float* bn1_g = (const float*)d_in[14];
    const float* bn1_b = (const float*)d_in[15];
    const float* bn1_m = (const float*)d_in[16];
    const float* bn1_v = (const float*)d_in[17];
    const float* bn2_g = (const float*)d_in[18];
    const float* bn2_b = (const float*)d_in[19];
    const float* bn2_m = (const float*)d_in[20];
    const float* bn2_v = (const float*)d_in[21];
    const float* bbias = (const float*)d_in[22];
    float* out = (float*)d_out;

    char* basep = (char*)d_ws;
    size_t off = 0;
    auto alloc = [&](size_t bytes) -> char* {
        char* p = basep + off;
        off = (off + bytes + 255) & ~(size_t)255;
        return p;
    };
    short* fcw_b  = (short*)alloc(400ULL * 37632 * 2);
    short* fc1w_b = (short*)alloc(864ULL * 416 * 2);
    float* xf     = (float*)alloc(2048ULL * 400 * 4);
    short* rb     = (short*)alloc(2048ULL * 416 * 2);
    float* kf     = (float*)alloc(2048ULL * 864 * 4);
    short* x1b    = (short*)alloc(2048ULL * 416 * 2);
    short* x2b    = (short*)alloc(2048ULL * 416 * 2);
    size_t fixed = off;

    int CHUNK = 128;
    for (int c = 2048; c >= 128; c >>= 1) {
        size_t need = fixed + ((size_t)c * 400 * 8 * 4 + 256) + ((size_t)c * 37632 * 2 + 256);
        if (need <= ws_size) { CHUNK = c; break; }
    }
    float* hpart = (float*)alloc((size_t)CHUNK * 400 * 8 * 4);
    short* flat  = (short*)alloc((size_t)CHUNK * 37632 * 2);

    // weights -> bf16 (recomputed each call; deterministic)
    cvt_fcw<<<2048, 256, 0, stream>>>(fc_w, fcw_b, 400 * 37632 / 4);
    cvt_fc1w_pad<<<(864 * 416 + 255) / 256, 256, 0, stream>>>(fc1_w, fc1w_b);

    const int KLEN = 37632 / 8;  // split-K segment (147 K-steps)

    for (int br = 0; br < 2; ++br) {
        const int* eidx = (br == 0) ? e1 : e2;
        const int* ridx = (br == 0) ? r1i : r2i;
        short* xob = (br == 0) ? x1b : x2b;

        gather_bn0<<<2048, 128, 0, stream>>>(E_w, eidx, bn0_g, bn0_b, bn0_m, bn0_v, xf);
        gather_r_pad<<<2048, 128, 0, stream>>>(R_w, ridx, rb);
        // k filters: (2048x400) @ (864x400)^T + fc1_b -> f32 (2048x864)
        gemm_bt<0><<<dim3(16, 7), 256, 0, stream>>>(rb, fc1w_b, kf, 2048, 864, 416, 864, fc1_b, 0);

        for (int cb = 0; cb < 2048; cb += CHUNK) {
            conv_bn1<<<CHUNK, 256, 0, stream>>>(xf, kf, bn1_g, bn1_b, bn1_m, bn1_v, flat, cb);
            // fc: (CHUNK x 37632) @ (400 x 37632)^T, split-K x8 partials
            gemm_bt<1><<<dim3(CHUNK / 128, 4, 8), 256, 0, stream>>>(
                flat, fcw_b, hpart, CHUNK, 400, 37632, 400, nullptr, KLEN);
            reduce_bn2<<<(CHUNK * 416 + 255) / 256, 256, 0, stream>>>(
                hpart, CHUNK, fc_b, bn2_g, bn2_b, bn2_m, bn2_v, xob, cb);
        }
    }

    // logits = x1 @ x2^T + b_bias[col]  -> f32 (2048x2048)
    gemm_bt<0><<<dim3(16, 16), 256, 0, stream>>>(x1b, x2b, out, 2048, 2048, 416, 2048, bbias, 0);
}

// Round 2
// 440.622 us; speedup vs baseline: 1.2022x; 1.2022x over previous
//
#include <hip/hip_runtime.h>
#include <hip/hip_bf16.h>
#include <stdint.h>

#define EPSF 1e-5f

typedef __attribute__((ext_vector_type(8))) short short8;
typedef __attribute__((ext_vector_type(4))) float f32x4;

__device__ inline short f2bf(float f) {
    union { float f; unsigned u; } x; x.f = f;
    unsigned u = x.u;
    unsigned r = (u + 0x7FFFu + ((u >> 16) & 1u)) >> 16;  // round-to-nearest-even
    return (short)r;
}

__device__ inline f32x4 mfma16x16x32(short8 a, short8 b, f32x4 c) {
    return __builtin_amdgcn_mfma_f32_16x16x32_bf16(a, b, c, 0, 0, 0);
}

// ---------------------------------------------------------------------------
// BT-GEMM: C[M,N] = A[M,KP] * B[N,KP]^T   (A,B bf16-as-short, KP % 32 == 0)
// MODE 0: full-K, C = f32, += bias[col] if bias != nullptr
// MODE 1: split-K over blockIdx.z (uneven segments), partials to C + z*M*ldc
// Tile: 128x128, BK=32, 4 waves (2x2), each wave 64x64 via 4x4 MFMA frags.
// LDS tile uses a 16B-block XOR swizzle (blk ^= (row>>1)&3), applied on the
// per-lane GLOBAL source address at staging (global_load_lds writes linear)
// and on the ds_read address — both-sides-or-neither (guide rule 21).
// ---------------------------------------------------------------------------
template <int MODE>
__global__ __launch_bounds__(256) void gemm_bt(
    const short* __restrict__ A, const short* __restrict__ B,
    float* __restrict__ C, int M, int N, int KP, int ldc,
    const float* __restrict__ bias)
{
    __shared__ alignas(16) short As[128 * 32];
    __shared__ alignas(16) short Bs[128 * 32];

    const int tid = threadIdx.x;
    const int l   = tid & 63;
    const int w   = tid >> 6;
    const int wr  = w >> 1, wc = w & 1;
    const int m0  = blockIdx.x * 128;
    const int n0  = blockIdx.y * 128;

    int k_beg = 0, k_end = KP;
    if (MODE == 1) {
        int steps = KP >> 5;
        long long z = blockIdx.z;
        int s0 = (int)(z * steps / gridDim.z);
        int s1 = (int)((z + 1) * steps / gridDim.z);
        k_beg = s0 << 5;
        k_end = s1 << 5;
    }

    // staging geometry: lane l stages 16B to linear LDS slot (row sr, blk l&3)
    // but sources the LOGICAL block (l&3)^((sr>>1)&3) from global
    const int sr   = l >> 2;                         // row within 16-row group
    const int sc   = ((l & 3) ^ ((sr >> 1) & 3)) * 8; // swizzled global bf16-col
    // read geometry
    const int lr   = l & 15;                         // MFMA row/col lane index
    const int kg   = l >> 4;                         // MFMA k-group
    const int kswz = (kg ^ ((lr >> 1) & 3)) * 8;     // swizzled LDS bf16-col

    f32x4 acc[4][4] = {};

    for (int k0 = k_beg; k0 < k_end; k0 += 32) {
#pragma unroll
        for (int i = 0; i < 2; ++i) {
            const int g  = w * 2 + i;                 // 16-row group 0..7
            const int rA = m0 + g * 16 + sr;
            const short* ga = A + (size_t)rA * KP + k0 + sc;
            __builtin_amdgcn_global_load_lds(
                (const __attribute__((address_space(1))) void*)ga,
                (__attribute__((address_space(3))) void*)(&As[g * 512]), 16, 0, 0);
            int rB = n0 + g * 16 + sr;
            if (rB > N - 1) rB = N - 1;               // clamp: keep reads in-bounds
            const short* gb = B + (size_t)rB * KP + k0 + sc;
            __builtin_amdgcn_global_load_lds(
                (const __attribute__((address_space(1))) void*)gb,
                (__attribute__((address_space(3))) void*)(&Bs[g * 512]), 16, 0, 0);
        }
        __syncthreads();   // compiler drains vmcnt before s_barrier

        short8 af[4], bfr[4];
#pragma unroll
        for (int mi = 0; mi < 4; ++mi)
            af[mi] = *(const short8*)&As[(wr * 64 + mi * 16 + lr) * 32 + kswz];
#pragma unroll
        for (int ni = 0; ni < 4; ++ni)
            bfr[ni] = *(const short8*)&Bs[(wc * 64 + ni * 16 + lr) * 32 + kswz];
#pragma unroll
        for (int mi = 0; mi < 4; ++mi)
#pragma unroll
            for (int ni = 0; ni < 4; ++ni)
                acc[mi][ni] = mfma16x16x32(af[mi], bfr[ni], acc[mi][ni]);
        __syncthreads();
    }

    float* Cb = C;
    if (MODE == 1) Cb = C + (size_t)blockIdx.z * M * ldc;

#pragma unroll
    for (int ni = 0; ni < 4; ++ni) {
        int col = n0 + wc * 64 + ni * 16 + lr;
        if (col >= N) continue;
        float bv = (MODE == 0 && bias) ? bias[col] : 0.0f;
#pragma unroll
        for (int mi = 0; mi < 4; ++mi) {
            int row0 = m0 + wr * 64 + mi * 16 + kg * 4;
#pragma unroll
            for (int r = 0; r < 4; ++r)
                Cb[(size_t)(row0 + r) * ldc + col] = acc[mi][ni][r] + bv;
        }
    }
}

// ---------------------------------------------------------------------------
// fused gathers: entity row + BN0 -> f32 x[2048,400]; relation row -> bf16
// padded to 416 cols
// ---------------------------------------------------------------------------
__global__ void gather_fused(const float* __restrict__ E, const int* __restrict__ eidx,
                             const float* __restrict__ R, const int* __restrict__ ridx,
                             const float* g, const float* bb, const float* m,
                             const float* v, float* __restrict__ xout,
                             short* __restrict__ rout)
{
    int b = blockIdx.x;
    int e = eidx[b];
    float s = g[0] * rsqrtf(v[0] + EPSF);
    float t = bb[0] - m[0] * s;
    const float4* src = (const float4*)(E + (size_t)e * 400);
    float4* dst = (float4*)(xout + (size_t)b * 400);
    for (int i = threadIdx.x; i < 100; i += blockDim.x) {
        float4 u = src[i];
        dst[i] = make_float4(u.x * s + t, u.y * s + t, u.z * s + t, u.w * s + t);
    }
    int r = ridx[b];
    const float* rsrc = R + (size_t)r * 400;
    short* rdst = rout + (size_t)b * 416;
    for (int i = threadIdx.x; i < 416; i += blockDim.x)
        rdst[i] = (i < 400) ? f2bf(rsrc[i]) : (short)0;
}

// fc_w (400 x 37632) f32 -> bf16, same layout
__global__ void cvt_fcw(const float* __restrict__ in, short* __restrict__ out, int n4)
{
    int i = blockIdx.x * blockDim.x + threadIdx.x;
    int stride = gridDim.x * blockDim.x;
    const float4* in4 = (const float4*)in;
    short4* out4 = (short4*)out;
    for (; i < n4; i += stride) {
        float4 v = in4[i];
        out4[i] = make_short4(f2bf(v.x), f2bf(v.y), f2bf(v.z), f2bf(v.w));
    }
}

// fc1_w (864 x 400) f32 -> bf16 padded to ld 416
__global__ void cvt_fc1w_pad(const float* __restrict__ in, short* __restrict__ out)
{
    int i = blockIdx.x * blockDim.x + threadIdx.x;
    if (i >= 864 * 416) return;
    int row = i / 416, col = i - row * 416;
    out[i] = (col < 400) ? f2bf(in[row * 400 + col]) : (short)0;
}

// ---------------------------------------------------------------------------
// per-sample conv (96 out-ch, 9 taps, valid) + BN1 -> bf16 flat[b, o*392+l]
// one block per sample; short8 (16B) vectorized stores
// ---------------------------------------------------------------------------
__global__ __launch_bounds__(256) void conv_bn1(
    const float* __restrict__ xall, const float* __restrict__ kfall,
    const float* __restrict__ g1, const float* __restrict__ b1,
    const float* __restrict__ m1, const float* __restrict__ v1,
    short* __restrict__ flat, int b_base)
{
    __shared__ float xs[400];
    __shared__ float ks[864];
    __shared__ float s1s[96], t1s[96];
    const int b = b_base + blockIdx.x;
    const int tid = threadIdx.x;
    const float* xr = xall + (size_t)b * 400;
    const float* kr = kfall + (size_t)b * 864;
    for (int i = tid; i < 400; i += 256) xs[i] = xr[i];
    for (int i = tid; i < 864; i += 256) ks[i] = kr[i];
    if (tid < 96) {
        float s = g1[tid] * rsqrtf(v1[tid] + EPSF);
        s1s[tid] = s;
        t1s[tid] = b1[tid] - m1[tid] * s;
    }
    __syncthreads();
    short8* fr8 = (short8*)(flat + (size_t)blockIdx.x * 37632);
    for (int i = tid; i < 4704; i += 256) {     // 4704 = 96*392/8
        int o   = i / 49;                       // 392/8 = 49 vectors per channel
        int ll0 = (i - o * 49) * 8;
        const float* kk = &ks[o * 9];
        float xv[16];
#pragma unroll
        for (int j = 0; j < 16; ++j) xv[j] = xs[ll0 + j];
        float s1 = s1s[o], t1 = t1s[o];
        short8 outv;
#pragma unroll
        for (int j = 0; j < 8; ++j) {
            float a = 0.f;
#pragma unroll
            for (int f = 0; f < 9; ++f) a += xv[j + f] * kk[f];
            outv[j] = f2bf(a * s1 + t1);
        }
        fr8[i] = outv;
    }
}

// sum NZ split-K partials + fc_b + BN2 + ReLU -> bf16 x_out rows, ld 416 (pad=0)
__global__ void reduce_bn2(const float* __restrict__ hp, int C, int nz,
                           const float* __restrict__ fcb,
                           const float* __restrict__ g2, const float* __restrict__ b2,
                           const float* __restrict__ m2, const float* __restrict__ v2,
                           short* __restrict__ xout, int cb)
{
    int i = blockIdx.x * blockDim.x + threadIdx.x;
    int total = C * 416;
    if (i >= total) return;
    int row = i / 416, col = i - row * 416;
    short val = 0;
    if (col < 400) {
        float s = 0.f;
        size_t stride = (size_t)C * 400;
        size_t basei = (size_t)row * 400 + col;
        for (int k = 0; k < nz; ++k) s += hp[k * stride + basei];
        float sc = g2[col] * rsqrtf(v2[col] + EPSF);
        float hv = (s + fcb[col] - m2[col]) * sc + b2[col];
        val = f2bf(fmaxf(hv, 0.f));
    }
    xout[(size_t)(cb + row) * 416 + col] = val;
}

extern "C" void kernel_launch(void* const* d_in, const int* in_sizes, int n_in,
                              void* d_out, int out_size, void* d_ws, size_t ws_size,
                              hipStream_t stream)
{
    (void)in_sizes; (void)n_in; (void)out_size;
    const int*   e1    = (const int*)d_in[0];
    const int*   r1i   = (const int*)d_in[1];
    const int*   r2i   = (const int*)d_in[2];
    const int*   e2    = (const int*)d_in[3];
    const float* E_w   = (const float*)d_in[4];
    const float* R_w   = (const float*)d_in[5];
    const float* fc1_w = (const float*)d_in[6];
    const float* fc1_b = (const float*)d_in[7];
    const float* fc_w  = (const float*)d_in[8];
    const float* fc_b  = (const float*)d_in[9];
    const float* bn0_g = (const float*)d_in[10];
    const float* bn0_b = (const float*)d_in[11];
    const float* bn0_m = (const float*)d_in[12];
    const float* bn0_v = (const float*)d_in[13];
    const float* bn1_g = (const float*)d_in[14];
    const float* bn1_b = (const float*)d_in[15];
    const float* bn1_m = (const float*)d_in[16];
    const float* bn1_v = (const float*)d_in[17];
    const float* bn2_g = (const float*)d_in[18];
    const float* bn2_b = (const float*)d_in[19];
    const float* bn2_m = (const float*)d_in[20];
    const float* bn2_v = (const float*)d_in[21];
    const float* bbias = (const float*)d_in[22];
    float* out = (float*)d_out;

    char* basep = (char*)d_ws;
    size_t off = 0;
    auto alloc = [&](size_t bytes) -> char* {
        char* p = basep + off;
        off = (off + bytes + 255) & ~(size_t)255;
        return p;
    };
    short* fcw_b  = (short*)alloc(400ULL * 37632 * 2);
    short* fc1w_b = (short*)alloc(864ULL * 416 * 2);
    float* xf     = (float*)alloc(2048ULL * 400 * 4);
    short* rb     = (short*)alloc(2048ULL * 416 * 2);
    float* kf     = (float*)alloc(2048ULL * 864 * 4);
    short* x1b    = (short*)alloc(2048ULL * 416 * 2);
    short* x2b    = (short*)alloc(2048ULL * 416 * 2);
    size_t fixed = off;

    const int NZ = 16;  // split-K ways for the big fc GEMM (4 blocks/CU)
    int CHUNK = 128;
    for (int c = 2048; c >= 128; c >>= 1) {
        size_t need = fixed + ((size_t)c * 400 * NZ * 4 + 256) + ((size_t)c * 37632 * 2 + 256);
        if (need <= ws_size) { CHUNK = c; break; }
    }
    float* hpart = (float*)alloc((size_t)CHUNK * 400 * NZ * 4);
    short* flat  = (short*)alloc((size_t)CHUNK * 37632 * 2);

    // weights -> bf16 (recomputed each call; deterministic)
    cvt_fcw<<<2048, 256, 0, stream>>>(fc_w, fcw_b, 400 * 37632 / 4);
    cvt_fc1w_pad<<<(864 * 416 + 255) / 256, 256, 0, stream>>>(fc1_w, fc1w_b);

    for (int br = 0; br < 2; ++br) {
        const int* eidx = (br == 0) ? e1 : e2;
        const int* ridx = (br == 0) ? r1i : r2i;
        short* xob = (br == 0) ? x1b : x2b;

        gather_fused<<<2048, 128, 0, stream>>>(E_w, eidx, R_w, ridx,
                                               bn0_g, bn0_b, bn0_m, bn0_v, xf, rb);
        // k filters: (2048x400) @ (864x400)^T + fc1_b -> f32 (2048x864)
        gemm_bt<0><<<dim3(16, 7), 256, 0, stream>>>(rb, fc1w_b, kf, 2048, 864, 416, 864, fc1_b);

        for (int cb = 0; cb < 2048; cb += CHUNK) {
            conv_bn1<<<CHUNK, 256, 0, stream>>>(xf, kf, bn1_g, bn1_b, bn1_m, bn1_v, flat, cb);
            // fc: (CHUNK x 37632) @ (400 x 37632)^T, split-K x NZ partials
            gemm_bt<1><<<dim3(CHUNK / 128, 4, NZ), 256, 0, stream>>>(
                flat, fcw_b, hpart, CHUNK, 400, 37632, 400, nullptr);
            reduce_bn2<<<(CHUNK * 416 + 255) / 256, 256, 0, stream>>>(
                hpart, CHUNK, NZ, fc_b, bn2_g, bn2_b, bn2_m, bn2_v, xob, cb);
        }
    }

    // logits = x1 @ x2^T + b_bias[col]  -> f32 (2048x2048)
    gemm_bt<0><<<dim3(16, 16), 256, 0, stream>>>(x1b, x2b, out, 2048, 2048, 416, 2048, bbias);
}

// Round 3
// 372.095 us; speedup vs baseline: 1.4236x; 1.1842x over previous
//
#include <hip/hip_runtime.h>
#include <hip/hip_bf16.h>
#include <stdint.h>

#define EPSF 1e-5f

typedef __attribute__((ext_vector_type(8))) short short8;
typedef __attribute__((ext_vector_type(4))) float f32x4;

__device__ inline short f2bf(float f) {
    union { float f; unsigned u; } x; x.f = f;
    unsigned u = x.u;
    unsigned r = (u + 0x7FFFu + ((u >> 16) & 1u)) >> 16;  // round-to-nearest-even
    return (short)r;
}

__device__ inline f32x4 mfma16x16x32(short8 a, short8 b, f32x4 c) {
    return __builtin_amdgcn_mfma_f32_16x16x32_bf16(a, b, c, 0, 0, 0);
}

// ---------------------------------------------------------------------------
// BT-GEMM: C[M,N] = A[M,KP] * B[N,KP]^T   (A,B bf16-as-short, KP % 32 == 0)
// MODE 0: full-K, C = f32, += bias[col] if bias != nullptr
// MODE 1: split-K over blockIdx.z (uneven segments), partials to C + z*M*ldc
// Tile: 128x128, BK=32, 4 waves (2x2), each wave 64x64 via 4x4 MFMA frags.
// 3-deep LDS pipeline (T3+T4): stage(t+2) issued at step t; counted
// s_waitcnt vmcnt(4) (never 0 mid-loop) + raw s_barrier; trailing
// lgkmcnt(0) drains this wave's ds_reads before the buffer is recycled.
// 16B-block XOR swizzle applied on BOTH sides (global src + ds_read addr).
// ---------------------------------------------------------------------------
template <int MODE>
__global__ __launch_bounds__(256) void gemm_bt(
    const short* __restrict__ A, const short* __restrict__ B,
    float* __restrict__ C, int M, int N, int KP, int ldc,
    const float* __restrict__ bias)
{
    __shared__ alignas(16) short As[3][128 * 32];
    __shared__ alignas(16) short Bs[3][128 * 32];

    const int tid = threadIdx.x;
    const int l   = tid & 63;
    const int w   = tid >> 6;
    const int wr  = w >> 1, wc = w & 1;
    const int m0  = blockIdx.x * 128;
    const int n0  = blockIdx.y * 128;

    int k_beg = 0, k_end = KP;
    if (MODE == 1) {
        int steps = KP >> 5;
        long long z = blockIdx.z;
        int s0 = (int)(z * steps / gridDim.z);
        int s1 = (int)((z + 1) * steps / gridDim.z);
        k_beg = s0 << 5;
        k_end = s1 << 5;
    }

    // staging geometry: lane l stages 16B to linear LDS slot (row sr, blk l&3)
    // sourcing the LOGICAL block (l&3)^((sr>>1)&3) from global
    const int sr   = l >> 2;
    const int sc   = ((l & 3) ^ ((sr >> 1) & 3)) * 8;
    // read geometry (same XOR on the LDS side)
    const int lr   = l & 15;
    const int kg   = l >> 4;
    const int kswz = (kg ^ ((lr >> 1) & 3)) * 8;

    const short* gaBase = A + (size_t)(m0 + (w * 2) * 16 + sr) * KP + sc;
    int rB0 = n0 + (w * 2) * 16 + sr;      // B rows, clamped to stay in-bounds
    int rB1 = rB0 + 16;
    if (rB0 > N - 1) rB0 = N - 1;
    if (rB1 > N - 1) rB1 = N - 1;
    const short* gbBase0 = B + (size_t)rB0 * KP + sc;
    const short* gbBase1 = B + (size_t)rB1 * KP + sc;

    auto stage = [&](int buf, int k0) {
        const int g = w * 2;
        __builtin_amdgcn_global_load_lds(
            (const __attribute__((address_space(1))) void*)(gaBase + k0),
            (__attribute__((address_space(3))) void*)(&As[buf][g * 512]), 16, 0, 0);
        __builtin_amdgcn_global_load_lds(
            (const __attribute__((address_space(1))) void*)(gbBase0 + k0),
            (__attribute__((address_space(3))) void*)(&Bs[buf][g * 512]), 16, 0, 0);
        __builtin_amdgcn_global_load_lds(
            (const __attribute__((address_space(1))) void*)(gaBase + (size_t)16 * KP + k0),
            (__attribute__((address_space(3))) void*)(&As[buf][(g + 1) * 512]), 16, 0, 0);
        __builtin_amdgcn_global_load_lds(
            (const __attribute__((address_space(1))) void*)(gbBase1 + k0),
            (__attribute__((address_space(3))) void*)(&Bs[buf][(g + 1) * 512]), 16, 0, 0);
    };

    f32x4 acc[4][4] = {};

    const int nt = (k_end - k_beg) >> 5;
    stage(0, k_beg);
    if (nt > 1) stage(1, k_beg + 32);

    int rd = 0;
    for (int t = 0; t < nt; ++t) {
        if (t + 1 < nt) { asm volatile("s_waitcnt vmcnt(4)" ::: "memory"); }
        else            { asm volatile("s_waitcnt vmcnt(0)" ::: "memory"); }
        __builtin_amdgcn_s_barrier();
        __builtin_amdgcn_sched_barrier(0);

        if (t + 2 < nt) {
            int wb = rd + 2; if (wb >= 3) wb -= 3;
            stage(wb, k_beg + ((t + 2) << 5));
        }

        short8 af[4], bfr[4];
#pragma unroll
        for (int mi = 0; mi < 4; ++mi)
            af[mi] = *(const short8*)&As[rd][(wr * 64 + mi * 16 + lr) * 32 + kswz];
#pragma unroll
        for (int ni = 0; ni < 4; ++ni)
            bfr[ni] = *(const short8*)&Bs[rd][(wc * 64 + ni * 16 + lr) * 32 + kswz];
#pragma unroll
        for (int mi = 0; mi < 4; ++mi)
#pragma unroll
            for (int ni = 0; ni < 4; ++ni)
                acc[mi][ni] = mfma16x16x32(af[mi], bfr[ni], acc[mi][ni]);

        asm volatile("s_waitcnt lgkmcnt(0)" ::: "memory");
        if (++rd == 3) rd = 0;
    }

    float* Cb = C;
    if (MODE == 1) Cb = C + (size_t)blockIdx.z * M * ldc;

#pragma unroll
    for (int ni = 0; ni < 4; ++ni) {
        int col = n0 + wc * 64 + ni * 16 + lr;
        if (col >= N) continue;
        float bv = (MODE == 0 && bias) ? bias[col] : 0.0f;
#pragma unroll
        for (int mi = 0; mi < 4; ++mi) {
            int row0 = m0 + wr * 64 + mi * 16 + kg * 4;
#pragma unroll
            for (int r = 0; r < 4; ++r)
                Cb[(size_t)(row0 + r) * ldc + col] = acc[mi][ni][r] + bv;
        }
    }
}

// ---------------------------------------------------------------------------
// fused gathers: entity row + BN0 -> f32 x[2048,400]; relation row -> bf16
// padded to 416 cols
// ---------------------------------------------------------------------------
__global__ void gather_fused(const float* __restrict__ E, const int* __restrict__ eidx,
                             const float* __restrict__ R, const int* __restrict__ ridx,
                             const float* g, const float* bb, const float* m,
                             const float* v, float* __restrict__ xout,
                             short* __restrict__ rout)
{
    int b = blockIdx.x;
    int e = eidx[b];
    float s = g[0] * rsqrtf(v[0] + EPSF);
    float t = bb[0] - m[0] * s;
    const float4* src = (const float4*)(E + (size_t)e * 400);
    float4* dst = (float4*)(xout + (size_t)b * 400);
    for (int i = threadIdx.x; i < 100; i += blockDim.x) {
        float4 u = src[i];
        dst[i] = make_float4(u.x * s + t, u.y * s + t, u.z * s + t, u.w * s + t);
    }
    int r = ridx[b];
    const float* rsrc = R + (size_t)r * 400;
    short* rdst = rout + (size_t)b * 416;
    for (int i = threadIdx.x; i < 416; i += blockDim.x)
        rdst[i] = (i < 400) ? f2bf(rsrc[i]) : (short)0;
}

// fc_w (400 x 37632) f32 -> bf16, same layout
__global__ void cvt_fcw(const float* __restrict__ in, short* __restrict__ out, int n4)
{
    int i = blockIdx.x * blockDim.x + threadIdx.x;
    int stride = gridDim.x * blockDim.x;
    const float4* in4 = (const float4*)in;
    short4* out4 = (short4*)out;
    for (; i < n4; i += stride) {
        float4 v = in4[i];
        out4[i] = make_short4(f2bf(v.x), f2bf(v.y), f2bf(v.z), f2bf(v.w));
    }
}

// fc1_w (864 x 400) f32 -> bf16 padded to ld 416
__global__ void cvt_fc1w_pad(const float* __restrict__ in, short* __restrict__ out)
{
    int i = blockIdx.x * blockDim.x + threadIdx.x;
    if (i >= 864 * 416) return;
    int row = i / 416, col = i - row * 416;
    out[i] = (col < 400) ? f2bf(in[row * 400 + col]) : (short)0;
}

// ---------------------------------------------------------------------------
// per-sample conv (96 out-ch, 9 taps, valid) + BN1 -> bf16 flat[b, o*392+l]
// one block per sample; float4 LDS reads, short8 stores
// ---------------------------------------------------------------------------
__global__ __launch_bounds__(256) void conv_bn1(
    const float* __restrict__ xall, const float* __restrict__ kfall,
    const float* __restrict__ g1, const float* __restrict__ b1,
    const float* __restrict__ m1, const float* __restrict__ v1,
    short* __restrict__ flat, int b_base)
{
    __shared__ float xs[400];
    __shared__ float ks[864];
    __shared__ float s1s[96], t1s[96];
    const int b = b_base + blockIdx.x;
    const int tid = threadIdx.x;
    const float* xr = xall + (size_t)b * 400;
    const float* kr = kfall + (size_t)b * 864;
    for (int i = tid; i < 400; i += 256) xs[i] = xr[i];
    for (int i = tid; i < 864; i += 256) ks[i] = kr[i];
    if (tid < 96) {
        float s = g1[tid] * rsqrtf(v1[tid] + EPSF);
        s1s[tid] = s;
        t1s[tid] = b1[tid] - m1[tid] * s;
    }
    __syncthreads();
    short8* fr8 = (short8*)(flat + (size_t)blockIdx.x * 37632);
    for (int i = tid; i < 4704; i += 256) {     // 4704 = 96*392/8
        int o   = i / 49;                       // 49 short8 vectors per channel
        int ll0 = (i - o * 49) * 8;             // multiple of 8 -> float4 aligned
        const float* kk = &ks[o * 9];
        float xv[16];
        const float4* xp = (const float4*)&xs[ll0];
#pragma unroll
        for (int q = 0; q < 4; ++q) {
            float4 u = xp[q];
            xv[q * 4 + 0] = u.x; xv[q * 4 + 1] = u.y;
            xv[q * 4 + 2] = u.z; xv[q * 4 + 3] = u.w;
        }
        float s1 = s1s[o], t1 = t1s[o];
        short8 outv;
#pragma unroll
        for (int j = 0; j < 8; ++j) {
            float a = 0.f;
#pragma unroll
            for (int f = 0; f < 9; ++f) a += xv[j + f] * kk[f];
            outv[j] = f2bf(a * s1 + t1);
        }
        fr8[i] = outv;
    }
}

// sum NZ split-K partials + fc_b + BN2 + ReLU -> bf16 x_out rows, ld 416 (pad=0)
__global__ void reduce_bn2(const float* __restrict__ hp, int C, int nz,
                           const float* __restrict__ fcb,
                           const float* __restrict__ g2, const float* __restrict__ b2,
                           const float* __restrict__ m2, const float* __restrict__ v2,
                           short* __restrict__ xout, int cb)
{
    int i = blockIdx.x * blockDim.x + threadIdx.x;
    int total = C * 416;
    if (i >= total) return;
    int row = i / 416, col = i - row * 416;
    short val = 0;
    if (col < 400) {
        float s = 0.f;
        size_t stride = (size_t)C * 400;
        size_t basei = (size_t)row * 400 + col;
        for (int k = 0; k < nz; ++k) s += hp[k * stride + basei];
        float sc = g2[col] * rsqrtf(v2[col] + EPSF);
        float hv = (s + fcb[col] - m2[col]) * sc + b2[col];
        val = f2bf(fmaxf(hv, 0.f));
    }
    xout[(size_t)(cb + row) * 416 + col] = val;
}

extern "C" void kernel_launch(void* const* d_in, const int* in_sizes, int n_in,
                              void* d_out, int out_size, void* d_ws, size_t ws_size,
                              hipStream_t stream)
{
    (void)in_sizes; (void)n_in; (void)out_size;
    const int*   e1    = (const int*)d_in[0];
    const int*   r1i   = (const int*)d_in[1];
    const int*   r2i   = (const int*)d_in[2];
    const int*   e2    = (const int*)d_in[3];
    const float* E_w   = (const float*)d_in[4];
    const float* R_w   = (const float*)d_in[5];
    const float* fc1_w = (const float*)d_in[6];
    const float* fc1_b = (const float*)d_in[7];
    const float* fc_w  = (const float*)d_in[8];
    const float* fc_b  = (const float*)d_in[9];
    const float* bn0_g = (const float*)d_in[10];
    const float* bn0_b = (const float*)d_in[11];
    const float* bn0_m = (const float*)d_in[12];
    const float* bn0_v = (const float*)d_in[13];
    const float* bn1_g = (const float*)d_in[14];
    const float* bn1_b = (const float*)d_in[15];
    const float* bn1_m = (const float*)d_in[16];
    const float* bn1_v = (const float*)d_in[17];
    const float* bn2_g = (const float*)d_in[18];
    const float* bn2_b = (const float*)d_in[19];
    const float* bn2_m = (const float*)d_in[20];
    const float* bn2_v = (const float*)d_in[21];
    const float* bbias = (const float*)d_in[22];
    float* out = (float*)d_out;

    char* basep = (char*)d_ws;
    size_t off = 0;
    auto alloc = [&](size_t bytes) -> char* {
        char* p = basep + off;
        off = (off + bytes + 255) & ~(size_t)255;
        return p;
    };
    short* fcw_b  = (short*)alloc(400ULL * 37632 * 2);
    short* fc1w_b = (short*)alloc(864ULL * 416 * 2);
    float* xf     = (float*)alloc(2048ULL * 400 * 4);
    short* rb     = (short*)alloc(2048ULL * 416 * 2);
    float* kf     = (float*)alloc(2048ULL * 864 * 4);
    short* x1b    = (short*)alloc(2048ULL * 416 * 2);
    short* x2b    = (short*)alloc(2048ULL * 416 * 2);
    size_t fixed = off;

    const int NZ = 12;  // split-K ways: grid 16x4x12 = 768 = exactly 3 blocks/CU
    int CHUNK = 128;
    for (int c = 2048; c >= 128; c >>= 1) {
        size_t need = fixed + ((size_t)c * 400 * NZ * 4 + 256) + ((size_t)c * 37632 * 2 + 256);
        if (need <= ws_size) { CHUNK = c; break; }
    }
    float* hpart = (float*)alloc((size_t)CHUNK * 400 * NZ * 4);
    short* flat  = (short*)alloc((size_t)CHUNK * 37632 * 2);

    // weights -> bf16 (recomputed each call; deterministic)
    cvt_fcw<<<2048, 256, 0, stream>>>(fc_w, fcw_b, 400 * 37632 / 4);
    cvt_fc1w_pad<<<(864 * 416 + 255) / 256, 256, 0, stream>>>(fc1_w, fc1w_b);

    for (int br = 0; br < 2; ++br) {
        const int* eidx = (br == 0) ? e1 : e2;
        const int* ridx = (br == 0) ? r1i : r2i;
        short* xob = (br == 0) ? x1b : x2b;

        gather_fused<<<2048, 128, 0, stream>>>(E_w, eidx, R_w, ridx,
                                               bn0_g, bn0_b, bn0_m, bn0_v, xf, rb);
        // k filters: (2048x400) @ (864x400)^T + fc1_b -> f32 (2048x864)
        gemm_bt<0><<<dim3(16, 7), 256, 0, stream>>>(rb, fc1w_b, kf, 2048, 864, 416, 864, fc1_b);

        for (int cb = 0; cb < 2048; cb += CHUNK) {
            conv_bn1<<<CHUNK, 256, 0, stream>>>(xf, kf, bn1_g, bn1_b, bn1_m, bn1_v, flat, cb);
            // fc: (CHUNK x 37632) @ (400 x 37632)^T, split-K x NZ partials
            gemm_bt<1><<<dim3(CHUNK / 128, 4, NZ), 256, 0, stream>>>(
                flat, fcw_b, hpart, CHUNK, 400, 37632, 400, nullptr);
            reduce_bn2<<<(CHUNK * 416 + 255) / 256, 256, 0, stream>>>(
                hpart, CHUNK, NZ, fc_b, bn2_g, bn2_b, bn2_m, bn2_v, xob, cb);
        }
    }

    // logits = x1 @ x2^T + b_bias[col]  -> f32 (2048x2048)
    gemm_bt<0><<<dim3(16, 16), 256, 0, stream>>>(x1b, x2b, out, 2048, 2048, 416, 2048, bbias);
}